// Round 8
// baseline (169.765 us; speedup 1.0000x reference)
//
#include <hip/hip_runtime.h>

#define NNODES 200000
#define NEDGES 3200000
#define NGRAPH 100
#define NPG    2000
#define D      128
#define DOUT   64
#define CAP1   4096     // max distinct layer-1 nodes (expected ~1600)
#define CAP2   8192     // max edges into fetched nodes (expected ~1600)
#define CAPE   65536    // max edges into S1 nodes (expected ~25600)
#define FBUF   1024     // per-block LDS compaction buffer
#define LJMAX  256      // per-graph e2 edge cap (expected ~16)

// ---- init: zero deg/need/counters/agg1, -1 the s1 index map ----
__global__ void prek(int* deg, int* s1idx, unsigned char* need, float* agg1, int* cnt) {
    int n = blockIdx.x * blockDim.x + threadIdx.x;   // grid covers 524288
    if (n < NNODES) { deg[n] = 0; s1idx[n] = -1; need[n] = 0; }
    if (n < CAP1 * D) agg1[n] = 0.0f;
    if (n < 8) cnt[n] = 0;
}

// ---- scan 1: edges into fetched nodes (arithmetic membership),
//      collect (src,slot), inline-dedup sources into dense S1 ids ----
__global__ void passAC(const int* __restrict__ src, const int4* __restrict__ dst4,
                       const int* __restrict__ to_fetch,
                       int* e2src, int* e2slot, int* s1idx, int* s1nodes,
                       unsigned char* need, int* cnt) {
    __shared__ int tf[NGRAPH];
    __shared__ int lcnt, lbase;
    __shared__ int bufs[FBUF], bufj[FBUF];
    int tid = threadIdx.x;
    for (int i = tid; i < NGRAPH; i += blockDim.x) tf[i] = to_fetch[i];
    if (blockIdx.x == 0 && tid < NGRAPH) need[to_fetch[tid] + tid * NPG] = 1;
    if (tid == 0) lcnt = 0;
    __syncthreads();
    const int NV = NEDGES / 4;
    int stride = gridDim.x * blockDim.x;
    for (int v = blockIdx.x * blockDim.x + tid; v < NV; v += stride) {
        int4 d4 = dst4[v];
        int ds[4] = {d4.x, d4.y, d4.z, d4.w};
        #pragma unroll
        for (int q = 0; q < 4; ++q) {
            int d = ds[q];
            int slot = d / NPG;
            if (tf[slot] == d - slot * NPG) {
                int s = src[v * 4 + q];
                int p = atomicAdd(&lcnt, 1);
                if (p < FBUF) { bufs[p] = s; bufj[p] = slot; }
                bool win = (atomicCAS(&s1idx[s], -1, -2) == -1);
                unsigned long long mask = __ballot(win ? 1 : 0);
                if (mask) {
                    int lane = tid & 63;
                    int lead = __ffsll(mask) - 1;
                    int nw = __popcll(mask);
                    int base = 0;
                    if (lane == lead) base = atomicAdd(&cnt[1], nw);
                    base = __shfl(base, lead, 64);
                    if (win) {
                        int idx = base + __popcll(mask & ((1ull << lane) - 1ull));
                        if (idx < CAP1) { s1idx[s] = idx; s1nodes[idx] = s; need[s] = 1; }
                        else s1idx[s] = -1;
                    }
                }
            }
        }
    }
    __syncthreads();
    {
        int n = min(lcnt, FBUF);
        if (tid == 0) lbase = atomicAdd(&cnt[0], n);
        __syncthreads();
        for (int k = tid; k < n; k += blockDim.x) {
            int g = lbase + k;
            if (g < CAP2) { e2src[g] = bufs[k]; e2slot[g] = bufj[k]; }
        }
    }
}

// ---- scan 2: edges into S1 nodes; collect, flag sources as needed ----
__global__ void passB(const int* __restrict__ src, const int4* __restrict__ dst4,
                      const int* __restrict__ s1idx, unsigned char* need,
                      int* e1src, int* e1j, int* cnt) {
    __shared__ int lcnt, lbase;
    __shared__ int bufs[FBUF], bufj[FBUF];
    int tid = threadIdx.x;
    if (tid == 0) lcnt = 0;
    __syncthreads();
    const int NV = NEDGES / 4;
    int stride = gridDim.x * blockDim.x;
    for (int v = blockIdx.x * blockDim.x + tid; v < NV; v += stride) {
        int4 d4 = dst4[v];
        int ds[4] = {d4.x, d4.y, d4.z, d4.w};
        #pragma unroll
        for (int q = 0; q < 4; ++q) {
            int j = s1idx[ds[q]];
            if (j >= 0) {
                int s = src[v * 4 + q];
                need[s] = 1;                      // benign race
                int p = atomicAdd(&lcnt, 1);
                if (p < FBUF) { bufs[p] = s; bufj[p] = j; }
            }
        }
    }
    __syncthreads();
    {
        int n = min(lcnt, FBUF);                  // expected ~12/block, max ~60
        if (tid == 0) lbase = atomicAdd(&cnt[2], n);
        __syncthreads();
        for (int k = tid; k < n; k += blockDim.x) {
            int g = lbase + k;
            if (g < CAPE) { e1src[g] = bufs[k]; e1j[g] = bufj[k]; }
        }
    }
}

// ---- scan 3: degree count, only for needed nodes (~27K of 200K) ----
__global__ void passC(const int4* __restrict__ dst4, const unsigned char* __restrict__ need,
                      int* deg) {
    const int NV = NEDGES / 4;
    int stride = gridDim.x * blockDim.x;
    for (int v = blockIdx.x * blockDim.x + threadIdx.x; v < NV; v += stride) {
        int4 d4 = dst4[v];
        int ds[4] = {d4.x, d4.y, d4.z, d4.w};
        #pragma unroll
        for (int q = 0; q < 4; ++q)
            if (need[ds[q]]) atomicAdd(&deg[ds[q]], 1);
    }
}

// ---- layer-1 aggregation: agg1[j] += feat[s]*rsqrt(max(deg[s],1)) ----
__global__ void agg1_kernel(const int* __restrict__ e1src, const int* __restrict__ e1j,
                            const int* __restrict__ cnt, const int* __restrict__ deg,
                            const float* __restrict__ feat, float* agg1) {
    int col = threadIdx.x & 127, sub = threadIdx.x >> 7;   // 256 thr = 2 edge-lanes
    int ne = min(cnt[2], CAPE);
    for (int e = blockIdx.x * 2 + sub; e < ne; e += gridDim.x * 2) {
        int s = e1src[e];
        float nm = rsqrtf(fmaxf((float)deg[s], 1.0f));
        float v = feat[(size_t)s * D + col] * nm;
        atomicAdd(&agg1[e1j[e] * D + col], v);
    }
}

// ---- fused: per graph, recompute its ~16 h1 rows from agg1 (8-row w1 tiles),
//      sum them, layer-2 GEMM + relu, project with w3 ----
__global__ void ffinal(const int* __restrict__ e2src, const int* __restrict__ e2slot,
                       const int* __restrict__ s1idx, const int* __restrict__ cnt,
                       const float* __restrict__ agg1, const int* __restrict__ deg,
                       const int* __restrict__ to_fetch,
                       const float* __restrict__ w1, const float* __restrict__ b1,
                       const float* __restrict__ w2, const float* __restrict__ b2,
                       const float* __restrict__ w3, const float* __restrict__ b3,
                       float* __restrict__ out) {
    int i = blockIdx.x;                  // 0..99
    int t = threadIdx.x;                 // 128
    __shared__ int lj[LJMAX];
    __shared__ float lnm[LJMAX];
    __shared__ float sa[8][D];
    __shared__ float sv[D], h2[D];
    __shared__ int lc;
    if (t == 0) lc = 0;
    __syncthreads();
    int ne2 = min(cnt[0], CAP2);
    for (int e = t; e < ne2; e += blockDim.x) {       // gather this graph's e2 edges
        if (e2slot[e] == i) {
            int s = e2src[e];
            int j = s1idx[s];
            if (j >= 0) {
                int p = atomicAdd(&lc, 1);
                if (p < LJMAX) {
                    lj[p] = j;
                    lnm[p] = rsqrtf(fmaxf((float)deg[s], 1.0f));
                }
            }
        }
    }
    __syncthreads();
    int m = min(lc, LJMAX);
    float bb = b1[t];
    float hsum = 0.0f;
    for (int base = 0; base < m; base += 8) {          // 8-row tiles amortize w1
        int nr = min(8, m - base);
        __syncthreads();
        for (int x = t; x < 8 * D; x += blockDim.x) {
            int r = x >> 7, c = x & 127;
            sa[r][c] = (r < nr) ? agg1[lj[base + r] * D + c] : 0.0f;
        }
        __syncthreads();
        float a[8] = {0, 0, 0, 0, 0, 0, 0, 0};
        #pragma unroll 4
        for (int c = 0; c < D; c++) {
            float w = w1[c * D + t];
            #pragma unroll
            for (int r = 0; r < 8; r++) a[r] += sa[r][c] * w;
        }
        #pragma unroll
        for (int r = 0; r < 8; r++) {
            if (r < nr) {
                float nm = lnm[base + r];
                hsum += fmaxf(a[r] * nm + bb, 0.0f) * nm;
            }
        }
    }
    sv[t] = hsum;
    __syncthreads();
    float a2 = 0.0f;
    #pragma unroll 4
    for (int k = 0; k < D; k++) a2 += sv[k] * w2[k * D + t];
    float nm = rsqrtf(fmaxf((float)deg[to_fetch[i] + i * NPG], 1.0f));
    h2[t] = fmaxf(a2 * nm + b2[t], 0.0f);
    __syncthreads();
    if (t < DOUT) {
        float o = 0.0f;
        #pragma unroll 4
        for (int k = 0; k < D; k++) o += h2[k] * w3[t * D + k];
        out[i * DOUT + t] = o + b3[t];
    }
}

extern "C" void kernel_launch(void* const* d_in, const int* in_sizes, int n_in,
                              void* d_out, int out_size, void* d_ws, size_t ws_size,
                              hipStream_t stream) {
    const float* feat     = (const float*)d_in[0];
    const int*   src      = (const int*)  d_in[1];
    const int*   dst      = (const int*)  d_in[2];
    const int*   to_fetch = (const int*)  d_in[3];
    const float* w1       = (const float*)d_in[4];
    const float* b1       = (const float*)d_in[5];
    const float* w2       = (const float*)d_in[6];
    const float* b2       = (const float*)d_in[7];
    const float* w3       = (const float*)d_in[8];
    const float* b3       = (const float*)d_in[9];
    float* out = (float*)d_out;
    const int4* dst4 = (const int4*)dst;

    // workspace layout
    char* p = (char*)d_ws;
    int*   deg     = (int*)p;            p += (size_t)NNODES * 4;
    int*   s1idx   = (int*)p;            p += (size_t)NNODES * 4;
    int*   s1nodes = (int*)p;            p += (size_t)CAP1 * 4;
    int*   e2src   = (int*)p;            p += (size_t)CAP2 * 4;
    int*   e2slot  = (int*)p;            p += (size_t)CAP2 * 4;
    int*   e1src   = (int*)p;            p += (size_t)CAPE * 4;
    int*   e1j     = (int*)p;            p += (size_t)CAPE * 4;
    float* agg1    = (float*)p;          p += (size_t)CAP1 * D * 4;
    int*   cnt     = (int*)p;            p += 64;
    unsigned char* need = (unsigned char*)p; p += (size_t)NNODES;

    prek<<<(CAP1 * D + 255) / 256, 256, 0, stream>>>(deg, s1idx, need, agg1, cnt);
    passAC<<<2048, 256, 0, stream>>>(src, dst4, to_fetch, e2src, e2slot,
                                     s1idx, s1nodes, need, cnt);
    passB<<<2048, 256, 0, stream>>>(src, dst4, s1idx, need, e1src, e1j, cnt);
    passC<<<2048, 256, 0, stream>>>(dst4, need, deg);
    agg1_kernel<<<2048, 256, 0, stream>>>(e1src, e1j, cnt, deg, feat, agg1);
    ffinal<<<NGRAPH, 128, 0, stream>>>(e2src, e2slot, s1idx, cnt, agg1, deg,
                                       to_fetch, w1, b1, w2, b2, w3, b3, out);
}

// Round 9
// 149.336 us; speedup vs baseline: 1.1368x; 1.1368x over previous
//
#include <hip/hip_runtime.h>

#define NNODES 200000
#define NEDGES 3200000
#define NGRAPH 100
#define NPG    2000
#define D      128
#define DOUT   64
#define CAP1   4096     // max distinct layer-1 nodes (expected ~1600)
#define CAP2   8192     // max edges into fetched nodes (expected ~1600)
#define CAPE   65536    // max edges into S1 nodes (expected ~25600)
#define FBUF   1024     // per-block LDS compaction buffer

// ---- init: zero deg/need/counters/agg1/agg2, -1 the s1 index map ----
__global__ void prek(int* deg, int* s1idx, unsigned char* need,
                     float* agg1, float* agg2, int* cnt) {
    int n = blockIdx.x * blockDim.x + threadIdx.x;   // grid covers 524288
    if (n < NNODES) { deg[n] = 0; s1idx[n] = -1; need[n] = 0; }
    if (n < CAP1 * D) agg1[n] = 0.0f;
    if (n < NGRAPH * D) agg2[n] = 0.0f;
    if (n < 8) cnt[n] = 0;
}

// ---- scan 1: edges into fetched nodes (arithmetic membership),
//      collect (src,slot), inline-dedup sources into dense S1 ids ----
__global__ void passAC(const int* __restrict__ src, const int4* __restrict__ dst4,
                       const int* __restrict__ to_fetch,
                       int* e2src, int* e2slot, int* s1idx, int* s1nodes,
                       unsigned char* need, int* cnt) {
    __shared__ int tf[NGRAPH];
    __shared__ int lcnt, lbase;
    __shared__ int bufs[FBUF], bufj[FBUF];
    int tid = threadIdx.x;
    for (int i = tid; i < NGRAPH; i += blockDim.x) tf[i] = to_fetch[i];
    if (blockIdx.x == 0 && tid < NGRAPH) need[to_fetch[tid] + tid * NPG] = 1;
    if (tid == 0) lcnt = 0;
    __syncthreads();
    const int NV = NEDGES / 4;
    int stride = gridDim.x * blockDim.x;
    for (int v = blockIdx.x * blockDim.x + tid; v < NV; v += stride) {
        int4 d4 = dst4[v];
        int ds[4] = {d4.x, d4.y, d4.z, d4.w};
        #pragma unroll
        for (int q = 0; q < 4; ++q) {
            int d = ds[q];
            int slot = d / NPG;                       // magic-mul division
            if (tf[slot] == d - slot * NPG) {
                int s = src[v * 4 + q];
                int p = atomicAdd(&lcnt, 1);
                if (p < FBUF) { bufs[p] = s; bufj[p] = slot; }
                bool win = (atomicCAS(&s1idx[s], -1, -2) == -1);
                unsigned long long mask = __ballot(win ? 1 : 0);
                if (mask) {
                    int lane = tid & 63;
                    int lead = __ffsll(mask) - 1;
                    int nw = __popcll(mask);
                    int base = 0;
                    if (lane == lead) base = atomicAdd(&cnt[1], nw);
                    base = __shfl(base, lead, 64);
                    if (win) {
                        int idx = base + __popcll(mask & ((1ull << lane) - 1ull));
                        if (idx < CAP1) { s1idx[s] = idx; s1nodes[idx] = s; need[s] = 1; }
                        else s1idx[s] = -1;
                    }
                }
            }
        }
    }
    __syncthreads();
    {
        int n = min(lcnt, FBUF);
        if (tid == 0) lbase = atomicAdd(&cnt[0], n);
        __syncthreads();
        for (int k = tid; k < n; k += blockDim.x) {
            int g = lbase + k;
            if (g < CAP2) { e2src[g] = bufs[k]; e2slot[g] = bufj[k]; }
        }
    }
}

// ---- scan 2: edges into S1 nodes; collect, flag sources as needed ----
__global__ void passB(const int* __restrict__ src, const int4* __restrict__ dst4,
                      const int* __restrict__ s1idx, unsigned char* need,
                      int* e1src, int* e1j, int* cnt) {
    __shared__ int lcnt, lbase;
    __shared__ int bufs[FBUF], bufj[FBUF];
    int tid = threadIdx.x;
    if (tid == 0) lcnt = 0;
    __syncthreads();
    const int NV = NEDGES / 4;
    int stride = gridDim.x * blockDim.x;
    for (int v = blockIdx.x * blockDim.x + tid; v < NV; v += stride) {
        int4 d4 = dst4[v];
        int ds[4] = {d4.x, d4.y, d4.z, d4.w};
        #pragma unroll
        for (int q = 0; q < 4; ++q) {
            int j = s1idx[ds[q]];
            if (j >= 0) {
                int s = src[v * 4 + q];
                need[s] = 1;                      // benign race
                int p = atomicAdd(&lcnt, 1);
                if (p < FBUF) { bufs[p] = s; bufj[p] = j; }
            }
        }
    }
    __syncthreads();
    {
        int n = min(lcnt, FBUF);                  // expected ~12/block
        if (tid == 0) lbase = atomicAdd(&cnt[2], n);
        __syncthreads();
        for (int k = tid; k < n; k += blockDim.x) {
            int g = lbase + k;
            if (g < CAPE) { e1src[g] = bufs[k]; e1j[g] = bufj[k]; }
        }
    }
}

// ---- scan 3: degree count, only for needed nodes (~27K of 200K) ----
__global__ void passC(const int4* __restrict__ dst4, const unsigned char* __restrict__ need,
                      int* deg) {
    const int NV = NEDGES / 4;
    int stride = gridDim.x * blockDim.x;
    for (int v = blockIdx.x * blockDim.x + threadIdx.x; v < NV; v += stride) {
        int4 d4 = dst4[v];
        int ds[4] = {d4.x, d4.y, d4.z, d4.w};
        #pragma unroll
        for (int q = 0; q < 4; ++q)
            if (need[ds[q]]) atomicAdd(&deg[ds[q]], 1);
    }
}

// ---- layer-1 aggregation: agg1[j] += feat[s]*rsqrt(max(deg[s],1)) ----
__global__ void agg1_kernel(const int* __restrict__ e1src, const int* __restrict__ e1j,
                            const int* __restrict__ cnt, const int* __restrict__ deg,
                            const float* __restrict__ feat, float* agg1) {
    int t = threadIdx.x;                 // 128
    int ne = min(cnt[2], CAPE);
    for (int e = blockIdx.x; e < ne; e += gridDim.x) {
        int s = e1src[e];
        float nm = rsqrtf(fmaxf((float)deg[s], 1.0f));
        float v = feat[(size_t)s * D + t] * nm;
        atomicAdd(&agg1[e1j[e] * D + t], v);
    }
}

// ---- layer-1 GEMM + relu + pre-multiply next-layer norm (R3-proven shape) ----
__global__ void gemm1(const float* __restrict__ agg1, const float* __restrict__ w1,
                      const float* __restrict__ b1, const int* __restrict__ deg,
                      const int* __restrict__ s1nodes, const int* __restrict__ cnt,
                      float* h1n) {
    int nj = min(cnt[1], CAP1);
    int t = threadIdx.x;                 // 128
    __shared__ float sa[D];
    for (int j = blockIdx.x; j < nj; j += gridDim.x) {
        __syncthreads();
        sa[t] = agg1[j * D + t];
        __syncthreads();
        float acc = 0.0f;
        #pragma unroll
        for (int k = 0; k < D; k++) acc += sa[k] * w1[k * D + t];
        float nm = rsqrtf(fmaxf((float)deg[s1nodes[j]], 1.0f));
        h1n[j * D + t] = fmaxf(acc * nm + b1[t], 0.0f) * nm;
    }
}

// ---- layer-2 aggregation over the ~1600 fetched-node edges ----
__global__ void agg2_kernel(const int* __restrict__ e2src, const int* __restrict__ e2slot,
                            const int* __restrict__ s1idx, const int* __restrict__ cnt,
                            const float* __restrict__ h1n, float* agg2) {
    int t = threadIdx.x;                 // 128
    int ne = min(cnt[0], CAP2);
    for (int e = blockIdx.x; e < ne; e += gridDim.x) {
        int j = s1idx[e2src[e]];
        if (j >= 0) atomicAdd(&agg2[e2slot[e] * D + t], h1n[j * D + t]);
    }
}

// ---- layer-2 GEMM + relu, then out = h2 @ w3^T + b3 ----
__global__ void final_kernel(const float* __restrict__ agg2, const float* __restrict__ w2,
                             const float* __restrict__ b2, const int* __restrict__ deg,
                             const int* __restrict__ to_fetch,
                             const float* __restrict__ w3, const float* __restrict__ b3,
                             float* out) {
    int i = blockIdx.x;                  // 0..99
    int t = threadIdx.x;                 // 128
    __shared__ float sa[D], h2[D];
    sa[t] = agg2[i * D + t];
    __syncthreads();
    float acc = 0.0f;
    #pragma unroll
    for (int k = 0; k < D; k++) acc += sa[k] * w2[k * D + t];
    float nm = rsqrtf(fmaxf((float)deg[to_fetch[i] + i * NPG], 1.0f));
    h2[t] = fmaxf(acc * nm + b2[t], 0.0f);
    __syncthreads();
    if (t < DOUT) {
        float o = 0.0f;
        #pragma unroll
        for (int k = 0; k < D; k++) o += h2[k] * w3[t * D + k];
        out[i * DOUT + t] = o + b3[t];
    }
}

extern "C" void kernel_launch(void* const* d_in, const int* in_sizes, int n_in,
                              void* d_out, int out_size, void* d_ws, size_t ws_size,
                              hipStream_t stream) {
    const float* feat     = (const float*)d_in[0];
    const int*   src      = (const int*)  d_in[1];
    const int*   dst      = (const int*)  d_in[2];
    const int*   to_fetch = (const int*)  d_in[3];
    const float* w1       = (const float*)d_in[4];
    const float* b1       = (const float*)d_in[5];
    const float* w2       = (const float*)d_in[6];
    const float* b2       = (const float*)d_in[7];
    const float* w3       = (const float*)d_in[8];
    const float* b3       = (const float*)d_in[9];
    float* out = (float*)d_out;
    const int4* dst4 = (const int4*)dst;

    // workspace layout
    char* p = (char*)d_ws;
    int*   deg     = (int*)p;            p += (size_t)NNODES * 4;
    int*   s1idx   = (int*)p;            p += (size_t)NNODES * 4;
    int*   s1nodes = (int*)p;            p += (size_t)CAP1 * 4;
    int*   e2src   = (int*)p;            p += (size_t)CAP2 * 4;
    int*   e2slot  = (int*)p;            p += (size_t)CAP2 * 4;
    int*   e1src   = (int*)p;            p += (size_t)CAPE * 4;
    int*   e1j     = (int*)p;            p += (size_t)CAPE * 4;
    float* agg1    = (float*)p;          p += (size_t)CAP1 * D * 4;
    float* h1n     = (float*)p;          p += (size_t)CAP1 * D * 4;
    float* agg2    = (float*)p;          p += (size_t)NGRAPH * D * 4;
    int*   cnt     = (int*)p;            p += 64;
    unsigned char* need = (unsigned char*)p; p += (size_t)NNODES;

    prek<<<(CAP1 * D + 255) / 256, 256, 0, stream>>>(deg, s1idx, need, agg1, agg2, cnt);
    passAC<<<2048, 256, 0, stream>>>(src, dst4, to_fetch, e2src, e2slot,
                                     s1idx, s1nodes, need, cnt);
    passB<<<2048, 256, 0, stream>>>(src, dst4, s1idx, need, e1src, e1j, cnt);
    passC<<<2048, 256, 0, stream>>>(dst4, need, deg);
    agg1_kernel<<<2048, 128, 0, stream>>>(e1src, e1j, cnt, deg, feat, agg1);
    gemm1<<<CAP1, 128, 0, stream>>>(agg1, w1, b1, deg, s1nodes, cnt, h1n);
    agg2_kernel<<<1024, 128, 0, stream>>>(e2src, e2slot, s1idx, cnt, h1n, agg2);
    final_kernel<<<NGRAPH, 128, 0, stream>>>(agg2, w2, b2, deg, to_fetch, w3, b3, out);
}